// Round 2
// baseline (63.861 us; speedup 1.0000x reference)
//
#include <hip/hip_runtime.h>

// ExponentialTrajectoryFit, DIM = 8192, all float32.
//
// Rank-2 collapse of the reference:
//   d0=x1-x0, d1=x2-x1, d2=x3-x2; D1=[d0 d1], D2=[d1 d2] (8192x2).
//   M = D2 pinv(D1) = U V^T, U=D2, V^T = G^{-1} D1^T, G = D1^T D1 (2x2).
//   B = I - U V^T;  Woodbury: B^{-1} z = z + U (I2 - V^T U)^{-1} V^T z.
//   out = x0 - x* = (x0-x1) - (c0-a0)*d1 - (c1-a1)*d2
//   with a = G^{-1}[p0,p1], W = G^{-1}S (col0 = [0,1] exactly since
//   S col0 = D1^T d1 = G e2), t = G^{-1}(q - S a), c = (I2-W)^{-1} t.
// Needs only 9 dot products over DIM:
//   g00=d0.d0 g01=d0.d1 g11=d1.d1 s01=d0.d2 s11=d1.d2
//   p0=d0.x0 p1=d1.x0 q0=d0.x1 q1=d1.x1
//
// Single block, 1024 threads (16 waves, one CU). Each thread owns 2 float4
// chunks per input (coalesced 16B/lane), keeps all 32 floats in registers,
// f64 accumulation (exact vs the reference's f32 SVD+LU roundoff), wave
// butterfly + LDS cross-wave reduce, thread 0 does the 2x2 algebra, alpha/
// beta broadcast via LDS, epilogue written straight from registers — inputs
// are read exactly once.

#define ETF_NT  1024
#define ETF_NW  (ETF_NT / 64)   // 16 waves

__global__ __launch_bounds__(ETF_NT) void etf_fused_kernel(
    const float* __restrict__ x0, const float* __restrict__ x1,
    const float* __restrict__ x2, const float* __restrict__ x3,
    float* __restrict__ out) {
  const int t = threadIdx.x;

  const float4* X0 = reinterpret_cast<const float4*>(x0);
  const float4* X1 = reinterpret_cast<const float4*>(x1);
  const float4* X2 = reinterpret_cast<const float4*>(x2);
  const float4* X3 = reinterpret_cast<const float4*>(x3);

  // Issue all 8 global loads up-front; compiler emits back-to-back
  // global_load_dwordx4 then one s_waitcnt.
  float4 u0 = X0[t], v0 = X0[t + ETF_NT];
  float4 u1 = X1[t], v1 = X1[t + ETF_NT];
  float4 u2 = X2[t], v2 = X2[t + ETF_NT];
  float4 u3 = X3[t], v3 = X3[t + ETF_NT];

  // Compile-time-indexed unpack (fully unrolled below -> stays in VGPRs).
  float e0[8] = {u0.x, u0.y, u0.z, u0.w, v0.x, v0.y, v0.z, v0.w};
  float e1[8] = {u1.x, u1.y, u1.z, u1.w, v1.x, v1.y, v1.z, v1.w};
  float e2[8] = {u2.x, u2.y, u2.z, u2.w, v2.x, v2.y, v2.z, v2.w};
  float e3[8] = {u3.x, u3.y, u3.z, u3.w, v3.x, v3.y, v3.z, v3.w};

  double g00 = 0.0, g01 = 0.0, g11 = 0.0, s01 = 0.0, s11 = 0.0;
  double p0 = 0.0, p1 = 0.0, q0 = 0.0, q1 = 0.0;

#pragma unroll
  for (int k = 0; k < 8; ++k) {
    // Differences rounded in f32 first (matches the reference's f32 d
    // vectors exactly), then promoted for exact accumulation.
    double d0 = (double)(e1[k] - e0[k]);
    double d1 = (double)(e2[k] - e1[k]);
    double d2 = (double)(e3[k] - e2[k]);
    g00 += d0 * d0;
    g01 += d0 * d1;
    g11 += d1 * d1;
    s01 += d0 * d2;
    s11 += d1 * d2;
    p0 += d0 * (double)e0[k];
    p1 += d1 * (double)e0[k];
    q0 += d0 * (double)e1[k];
    q1 += d1 * (double)e1[k];
  }

  // 64-lane butterfly (double shuffles = 2x b32 each; latency-trivial here).
#pragma unroll
  for (int off = 32; off > 0; off >>= 1) {
    g00 += __shfl_down(g00, off);
    g01 += __shfl_down(g01, off);
    g11 += __shfl_down(g11, off);
    s01 += __shfl_down(s01, off);
    s11 += __shfl_down(s11, off);
    p0 += __shfl_down(p0, off);
    p1 += __shfl_down(p1, off);
    q0 += __shfl_down(q0, off);
    q1 += __shfl_down(q1, off);
  }

  __shared__ double red[ETF_NW][9];
  __shared__ float coef[2];

  const int wave = t >> 6;
  const int lane = t & 63;
  if (lane == 0) {
    red[wave][0] = g00; red[wave][1] = g01; red[wave][2] = g11;
    red[wave][3] = s01; red[wave][4] = s11;
    red[wave][5] = p0;  red[wave][6] = p1;
    red[wave][7] = q0;  red[wave][8] = q1;
  }
  __syncthreads();

  if (t == 0) {
    double G00 = 0, G01 = 0, G11 = 0, S01 = 0, S11 = 0;
    double P0 = 0, P1 = 0, Q0 = 0, Q1 = 0;
#pragma unroll
    for (int w = 0; w < ETF_NW; ++w) {
      G00 += red[w][0]; G01 += red[w][1]; G11 += red[w][2];
      S01 += red[w][3]; S11 += red[w][4];
      P0 += red[w][5];  P1 += red[w][6];
      Q0 += red[w][7];  Q1 += red[w][8];
    }
    // G^{-1} (2x2 symmetric)
    const double det = G00 * G11 - G01 * G01;
    const double inv = 1.0 / det;
    // a = G^{-1} D1^T x0
    const double a0 = (G11 * P0 - G01 * P1) * inv;
    const double a1 = (G00 * P1 - G01 * P0) * inv;
    // W = G^{-1} S; col 0 is exactly [0,1] (S col0 = G e2) -> only col 1.
    const double w01 = (G11 * S01 - G01 * S11) * inv;
    const double w11 = (G00 * S11 - G01 * S01) * inv;
    // r = D1^T z = D1^T x1 - S a;  S = [[g01,s01],[g11,s11]]
    const double r0 = Q0 - (G01 * a0 + S01 * a1);
    const double r1 = Q1 - (G11 * a0 + S11 * a1);
    // tvec = G^{-1} r = V^T z
    const double t0 = (G11 * r0 - G01 * r1) * inv;
    const double t1 = (G00 * r1 - G01 * r0) * inv;
    // c = (I2 - W)^{-1} tvec; I2-W = [[1,-w01],[-1,1-w11]],
    // detK = (1-w11)-w01, K^{-1} = [[1-w11, w01],[1, 1]]/detK.
    const double detK = (1.0 - w11) - w01;
    const double c0 = ((1.0 - w11) * t0 + w01 * t1) / detK;
    const double c1 = (t0 + t1) / detK;
    coef[0] = (float)(c0 - a0);  // alpha: multiplies d1 = x2-x1
    coef[1] = (float)(c1 - a1);  // beta:  multiplies d2 = x3-x2
  }
  __syncthreads();

  const float alpha = coef[0];
  const float beta = coef[1];

  // out = (x0-x1) - alpha*(x2-x1) - beta*(x3-x2); operands still in VGPRs.
  float4* O = reinterpret_cast<float4*>(out);
  float4 o;
  o.x = (u0.x - u1.x) - alpha * (u2.x - u1.x) - beta * (u3.x - u2.x);
  o.y = (u0.y - u1.y) - alpha * (u2.y - u1.y) - beta * (u3.y - u2.y);
  o.z = (u0.z - u1.z) - alpha * (u2.z - u1.z) - beta * (u3.z - u2.z);
  o.w = (u0.w - u1.w) - alpha * (u2.w - u1.w) - beta * (u3.w - u2.w);
  O[t] = o;
  o.x = (v0.x - v1.x) - alpha * (v2.x - v1.x) - beta * (v3.x - v2.x);
  o.y = (v0.y - v1.y) - alpha * (v2.y - v1.y) - beta * (v3.y - v2.y);
  o.z = (v0.z - v1.z) - alpha * (v2.z - v1.z) - beta * (v3.z - v2.z);
  o.w = (v0.w - v1.w) - alpha * (v2.w - v1.w) - beta * (v3.w - v2.w);
  O[t + ETF_NT] = o;
}

extern "C" void kernel_launch(void* const* d_in, const int* in_sizes, int n_in,
                              void* d_out, int out_size, void* d_ws, size_t ws_size,
                              hipStream_t stream) {
  const float* x0 = (const float*)d_in[0];
  const float* x1 = (const float*)d_in[1];
  const float* x2 = (const float*)d_in[2];
  const float* x3 = (const float*)d_in[3];
  float* out = (float*)d_out;
  (void)in_sizes; (void)n_in; (void)out_size; (void)d_ws; (void)ws_size;

  etf_fused_kernel<<<1, ETF_NT, 0, stream>>>(x0, x1, x2, x3, out);
}